// Round 13
// baseline (417.180 us; speedup 1.0000x reference)
//
#include <hip/hip_runtime.h>
#include <hip/hip_bf16.h>

#define P 7
#define CCH 256
#define NPIX 49
#define KTOT 2304
#define TILE 25088              // 49 * 512 bytes per level tile
#define ZOFF2 (2 * TILE)        // zero row offset (2-tile kernels)
#define LDS2 (2 * TILE + 512)   // two tiles + zero row
#define LDSK (TILE + 512)       // one tile + zero row
#define NIT 1568                // TILE/16 uint4 items

typedef __bf16 bf16x8 __attribute__((ext_vector_type(8)));
typedef float f32x4 __attribute__((ext_vector_type(4)));

__device__ __forceinline__ unsigned short f2bf(float f) {
    unsigned int u = __float_as_uint(f);
    unsigned int r = (u + 0x7fffu + ((u >> 16) & 1u)) >> 16;
    return (unsigned short)r;
}
__device__ __forceinline__ float blo(unsigned int u) { return __uint_as_float(u << 16); }
__device__ __forceinline__ float bhi(unsigned int u) { return __uint_as_float(u & 0xffff0000u); }

// NCHW f32 -> NHWC bf16 (per level), 32x32 tile transpose over (c,x)
__global__ void nhwc_transpose_kernel(const float* __restrict__ src,
                                      unsigned short* __restrict__ dst,
                                      int H, int W) {
    __shared__ float tile[32][33];
    int x0 = blockIdx.x * 32;
    int c0 = blockIdx.y * 32;
    int bz = blockIdx.z;            // b*H + y
    int b = bz / H, y = bz - b * H;
    int tx = threadIdx.x & 31, ty = threadIdx.x >> 5;   // 256 threads
    const float* s = src + ((size_t)(b * CCH + c0) * H + y) * W + x0;
#pragma unroll
    for (int j = 0; j < 4; ++j) {
        int row = ty + j * 8;
        tile[row][tx] = s[(size_t)row * H * W + tx];
    }
    __syncthreads();
    unsigned short* d = dst + ((size_t)bz * W + x0) * CCH + c0;
#pragma unroll
    for (int j = 0; j < 4; ++j) {
        int row = ty + j * 8;
        d[(size_t)row * CCH + tx] = f2bf(tile[tx][row]);
    }
}

// w[co][ci][ky][kx] f32 -> Bt[co][k] bf16 with k = (ky*3+kx)*256 + ci
__global__ void wtrans_kernel(const float* __restrict__ pre_w,
                              const float* __restrict__ post_w,
                              unsigned short* __restrict__ btpre,
                              unsigned short* __restrict__ btpost) {
    int idx = blockIdx.x * 256 + threadIdx.x;
    const int total = CCH * KTOT;
    if (idx >= 2 * total) return;
    const float* w = pre_w;
    unsigned short* o = btpre;
    int r = idx;
    if (r >= total) { r -= total; w = post_w; o = btpost; }
    int co = r / KTOT, k = r - co * KTOT;
    int t = k >> 8, ci = k & 255;
    o[r] = f2bf(w[(size_t)(co * CCH + ci) * 9 + t]);
}

// ============================================================================
// k1: RA only. One block = one (roi, level); 256 thr = 4 waves, bins stride 4.
// Writes pre-swizzled bf16 A-tile to ws.
// ============================================================================
__launch_bounds__(256)
__global__ void ra_stage_kernel(const float* __restrict__ rois,
                                const unsigned short* __restrict__ nh0,
                                const unsigned short* __restrict__ nh1,
                                const unsigned short* __restrict__ nh2,
                                const unsigned short* __restrict__ nh3,
                                const float* __restrict__ raw0,
                                const float* __restrict__ raw1,
                                const float* __restrict__ raw2,
                                const float* __restrict__ raw3,
                                int modes,
                                unsigned short* __restrict__ atile,
                                int nroi) {
    int bid  = blockIdx.x;
    int lev  = bid / nroi;
    int roi  = bid - lev * nroi;
    int tid  = threadIdx.x;
    int lane = tid & 63;
    int wv   = tid >> 6;        // 0..3
    int ch0  = lane * 4;

    const float* rp = rois + (size_t)roi * 6;
    int   bidx = (int)rp[0];
    float cx0 = rp[1], cy0 = rp[2], rw0 = rp[3], rh0 = rp[4], th = rp[5];
    float ct = cosf(th), st = sinf(th);

    const unsigned short* nhv[4] = {nh0, nh1, nh2, nh3};
    const float* rawv[4] = {raw0, raw1, raw2, raw3};
    const int Hs[4] = {256, 128, 64, 32};
    const float scl[4] = {0.25f, 0.125f, 0.0625f, 0.03125f};

    int H = Hs[lev], W = H;
    float s = scl[lev];
    float cx = cx0 * s, cy = cy0 * s, rw = rw0 * s, rh = rh0 * s;
    float bw = rw * (1.0f / P), bh = rh * (1.0f / P);
    float fH = (float)H, fW = (float)W;
    bool staged = (modes >> lev) & 1;
    const unsigned short* f = nhv[lev];
    const float* fr = rawv[lev];

    char* base = (char*)atile + ((size_t)lev * nroi + roi) * TILE;

    for (int bin = wv; bin < NPIX; bin += 4) {
        int py = bin / 7, px = bin - py * 7;
        float a0 = 0.f, a1 = 0.f, a2 = 0.f, a3 = 0.f;
#pragma unroll
        for (int smp = 0; smp < 4; ++smp) {
            int sy = smp >> 1, sx = smp & 1;
            float offy = (float)py + 0.25f + 0.5f * (float)sy;
            float offx = (float)px + 0.25f + 0.5f * (float)sx;
            float yy = offy * bh - rh * 0.5f;
            float xx = offx * bw - rw * 0.5f;
            float X = xx * ct + yy * st + cx;
            float Y = yy * ct - xx * st + cy;
            if (Y > -1.0f && Y < fH && X > -1.0f && X < fW) {
                float Yc = fmaxf(Y, 0.f), Xc = fmaxf(X, 0.f);
                int y0 = min((int)Yc, H - 1);
                int x0 = min((int)Xc, W - 1);
                int y1 = min(y0 + 1, H - 1), x1 = min(x0 + 1, W - 1);
                if (y0 >= H - 1) Yc = (float)(H - 1);
                if (x0 >= W - 1) Xc = (float)(W - 1);
                float ly = Yc - (float)y0, lx = Xc - (float)x0;
                float hy = 1.f - ly, hx = 1.f - lx;
                float w00 = hy * hx, w01 = hy * lx, w10 = ly * hx, w11 = ly * lx;
                if (staged) {
                    size_t r0 = (size_t)(bidx * H + y0) * W;
                    size_t r1 = (size_t)(bidx * H + y1) * W;
                    uint2 u00 = *(const uint2*)(f + ((r0 + x0) << 8) + ch0);
                    uint2 u01 = *(const uint2*)(f + ((r0 + x1) << 8) + ch0);
                    uint2 u10 = *(const uint2*)(f + ((r1 + x0) << 8) + ch0);
                    uint2 u11 = *(const uint2*)(f + ((r1 + x1) << 8) + ch0);
                    a0 += w00 * blo(u00.x) + w01 * blo(u01.x) + w10 * blo(u10.x) + w11 * blo(u11.x);
                    a1 += w00 * bhi(u00.x) + w01 * bhi(u01.x) + w10 * bhi(u10.x) + w11 * bhi(u11.x);
                    a2 += w00 * blo(u00.y) + w01 * blo(u01.y) + w10 * blo(u10.y) + w11 * blo(u11.y);
                    a3 += w00 * bhi(u00.y) + w01 * bhi(u01.y) + w10 * bhi(u10.y) + w11 * bhi(u11.y);
                } else {
                    size_t hw = (size_t)H * W;
                    size_t i00 = (size_t)y0 * W + x0, i01 = (size_t)y0 * W + x1;
                    size_t i10 = (size_t)y1 * W + x0, i11 = (size_t)y1 * W + x1;
                    const float* fp0 = fr + ((size_t)bidx * CCH + ch0) * hw;
                    float* accp[4] = {&a0, &a1, &a2, &a3};
#pragma unroll
                    for (int cc = 0; cc < 4; ++cc) {
                        const float* fp = fp0 + (size_t)cc * hw;
                        *accp[cc] += w00 * fp[i00] + w01 * fp[i01] + w10 * fp[i10] + w11 * fp[i11];
                    }
                }
            }
        }
        unsigned int q01 = (unsigned)f2bf(a0 * 0.25f) | ((unsigned)f2bf(a1 * 0.25f) << 16);
        unsigned int q23 = (unsigned)f2bf(a2 * 0.25f) | ((unsigned)f2bf(a3 * 0.25f) << 16);
        int off = bin * 512 + ((lane * 8) ^ ((bin & 7) << 4));
        *(uint2*)(base + off) = make_uint2(q01, q23);
    }
}

// ============================================================================
// k2a: pre-conv pairs, BOTH tiles LDS-resident. One block = (pair, roi).
// 512 thr = 8 waves, nt=2 (co, co+128). Per (t,c8): 2 B-loads feed 16 MFMAs
// (8:1). B register prefetch DEPTH 2 (even/odd slots, prefetch it+2).
// Pair partial = relu(lv0)+relu(lv1) in f32, written once.
// ============================================================================
__launch_bounds__(512, 4)
__global__ void pre_conv_pair_kernel(const unsigned short* __restrict__ atile,
                                     const unsigned short* __restrict__ btpre,
                                     const float* __restrict__ pre_b,
                                     float* __restrict__ part0,
                                     float* __restrict__ part1,
                                     int nroi) {
    __shared__ __align__(16) char lds[LDS2];

    int bid  = blockIdx.x;
    int pr   = bid / nroi;      // pair 0 -> levels {0,1}; pair 1 -> {2,3}
    int roi  = bid - pr * nroi;
    int tid  = threadIdx.x;
    int lane = tid & 63;
    int wv   = tid >> 6;        // 0..7
    int lrow = lane & 15;
    int lgrp = lane >> 4;       // 0..3
    int co0  = wv * 16 + lrow;  // 0..127
    int co1  = co0 + 128;

    if (tid < 128) ((float*)(lds + ZOFF2))[tid] = 0.f;

    // ---- stage both tiles of the pair ----
#pragma unroll
    for (int ml = 0; ml < 2; ++ml) {
        const uint4* s = (const uint4*)((const char*)atile +
                          ((size_t)(pr * 2 + ml) * nroi + roi) * TILE);
        uint4* d = (uint4*)(lds + ml * TILE);
        for (int i = tid; i < NIT; i += 512) d[i] = s[i];
    }
    __syncthreads();

    int pys[4], pxs[4];
    bool prow[4];
#pragma unroll
    for (int mt = 0; mt < 4; ++mt) {
        int pix = mt * 16 + lrow;
        pys[mt] = pix / 7;
        pxs[mt] = pix - pys[mt] * 7;
        prow[mt] = pix < NPIX;
    }
    int lg16 = lgrp * 16;

    const unsigned short* bp0 = btpre + (size_t)co0 * KTOT + lgrp * 8;
    const unsigned short* bp1 = btpre + (size_t)co1 * KTOT + lgrp * 8;

    f32x4 acc[2][4][2];   // [lv][mt][nt]
    {
        const f32x4 FZ = {0.f, 0.f, 0.f, 0.f};
#pragma unroll
        for (int lv = 0; lv < 2; ++lv)
#pragma unroll
            for (int mt = 0; mt < 4; ++mt) {
                acc[lv][mt][0] = FZ; acc[lv][mt][1] = FZ;
            }
    }

    // B register prefetch depth 2: slot A = even it, slot B = odd it
    bf16x8 b0A = *(const bf16x8*)(bp0);
    bf16x8 b1A = *(const bf16x8*)(bp1);
    bf16x8 b0B = *(const bf16x8*)(bp0 + 32);
    bf16x8 b1B = *(const bf16x8*)(bp1 + 32);

    for (int t = 0; t < 9; ++t) {
        int dy = t / 3 - 1, dx = (t % 3) - 1;
        int roff[4], swz[4];
#pragma unroll
        for (int mt = 0; mt < 4; ++mt) {
            int oy = pys[mt] + dy, ox = pxs[mt] + dx;
            bool v = prow[mt] && ((unsigned)oy < 7u) && ((unsigned)ox < 7u);
            int np = oy * 7 + ox;
            roff[mt] = v ? np * 512 : ZOFF2;
            swz[mt]  = v ? ((np & 7) << 4) : 16;
        }
#pragma unroll
        for (int c8 = 0; c8 < 8; ++c8) {
            int it  = t * 8 + c8;                 // parity == c8 parity
            int itn = (it + 2 <= 71) ? it + 2 : 71;
            bf16x8 n0 = *(const bf16x8*)(bp0 + itn * 32);
            bf16x8 n1 = *(const bf16x8*)(bp1 + itn * 32);
            bf16x8 b0 = (c8 & 1) ? b0B : b0A;
            bf16x8 b1 = (c8 & 1) ? b1B : b1A;
            int kb = c8 * 64 + lg16;
#pragma unroll
            for (int mt = 0; mt < 4; ++mt) {
                int lo = kb ^ swz[mt];
                bf16x8 a0 = *(const bf16x8*)(lds + roff[mt] + lo);
                bf16x8 a1 = *(const bf16x8*)(lds +
                              (roff[mt] == ZOFF2 ? ZOFF2 : roff[mt] + TILE) + lo);
                acc[0][mt][0] = __builtin_amdgcn_mfma_f32_16x16x32_bf16(a0, b0, acc[0][mt][0], 0, 0, 0);
                acc[0][mt][1] = __builtin_amdgcn_mfma_f32_16x16x32_bf16(a0, b1, acc[0][mt][1], 0, 0, 0);
                acc[1][mt][0] = __builtin_amdgcn_mfma_f32_16x16x32_bf16(a1, b0, acc[1][mt][0], 0, 0, 0);
                acc[1][mt][1] = __builtin_amdgcn_mfma_f32_16x16x32_bf16(a1, b1, acc[1][mt][1], 0, 0, 0);
            }
            if (c8 & 1) { b0B = n0; b1B = n1; }
            else        { b0A = n0; b1A = n1; }
        }
    }

    // ---- epilogue: f32 pair partial = relu(lv0)+relu(lv1), single store ----
    float bs0 = pre_b[co0], bs1 = pre_b[co1];
    float* og = (pr ? part1 : part0) + (size_t)roi * (NPIX * CCH);
#pragma unroll
    for (int mt = 0; mt < 4; ++mt)
#pragma unroll
        for (int r = 0; r < 4; ++r) {
            int pix = mt * 16 + lgrp * 4 + r;
            if (pix < NPIX) {
                float v0 = fmaxf(acc[0][mt][0][r] + bs0, 0.f)
                         + fmaxf(acc[1][mt][0][r] + bs0, 0.f);
                float v1 = fmaxf(acc[0][mt][1][r] + bs1, 0.f)
                         + fmaxf(acc[1][mt][1][r] + bs1, 0.f);
                og[pix * CCH + co0] = v0;
                og[pix * CCH + co1] = v1;
            }
        }
}

// ============================================================================
// k2b: post-conv. One block = (roi, cg of 128 co). Stage: sum f32 pair
// partials (single bf16 rounding) -> swizzled LDS tile -> conv nt=2 with
// B register prefetch depth 2 -> out.
// ============================================================================
__launch_bounds__(256, 6)
__global__ void post_conv_kernel(const float* __restrict__ part0,
                                 const float* __restrict__ part1,
                                 const unsigned short* __restrict__ btpost,
                                 const float* __restrict__ post_b,
                                 float* __restrict__ out) {
    __shared__ __align__(16) char lds[LDSK];

    int bid  = blockIdx.x;
    int roi  = bid >> 1;
    int cg   = bid & 1;
    int tid  = threadIdx.x;
    int lane = tid & 63;
    int wv   = tid >> 6;
    int lrow = lane & 15;
    int lgrp = lane >> 4;
    int co0  = cg * 128 + wv * 16 + lrow;
    int co1  = co0 + 64;

    if (tid < 128) ((float*)(lds + TILE))[tid] = 0.f;

    int pys[4], pxs[4];
    bool prow[4];
#pragma unroll
    for (int mt = 0; mt < 4; ++mt) {
        int pix = mt * 16 + lrow;
        pys[mt] = pix / 7;
        pxs[mt] = pix - pys[mt] * 7;
        prow[mt] = pix < NPIX;
    }
    int lg16 = lgrp * 16;

    // ---- stage: sum f32 pair partials -> bf16 swizzled tile ----
    {
        const float* p0 = part0 + (size_t)roi * (NPIX * CCH);
        const float* p1 = part1 + (size_t)roi * (NPIX * CCH);
        for (int i = tid; i < NPIX * CCH / 4; i += 256) {
            int e4 = i * 4;
            int pix = e4 >> 8, co = e4 & 255;
            float4 a = *(const float4*)(p0 + e4);
            float4 b = *(const float4*)(p1 + e4);
            float s0 = a.x + b.x, s1 = a.y + b.y;
            float s2 = a.z + b.z, s3 = a.w + b.w;
            unsigned q01 = (unsigned)f2bf(s0) | ((unsigned)f2bf(s1) << 16);
            unsigned q23 = (unsigned)f2bf(s2) | ((unsigned)f2bf(s3) << 16);
            *(uint2*)(lds + pix * 512 + ((co * 2) ^ ((pix & 7) << 4))) = make_uint2(q01, q23);
        }
    }
    __syncthreads();

    // ---- conv nt=2 with B prefetch depth 2 ----
    f32x4 acc[4][2];
    {
        const f32x4 FZ = {0.f, 0.f, 0.f, 0.f};
#pragma unroll
        for (int mt = 0; mt < 4; ++mt) { acc[mt][0] = FZ; acc[mt][1] = FZ; }
    }
    const unsigned short* bp0 = btpost + (size_t)co0 * KTOT + lgrp * 8;
    const unsigned short* bp1 = btpost + (size_t)co1 * KTOT + lgrp * 8;

    bf16x8 b0A = *(const bf16x8*)(bp0);
    bf16x8 b1A = *(const bf16x8*)(bp1);
    bf16x8 b0B = *(const bf16x8*)(bp0 + 32);
    bf16x8 b1B = *(const bf16x8*)(bp1 + 32);

    for (int t = 0; t < 9; ++t) {
        int dy = t / 3 - 1, dx = (t % 3) - 1;
        int roff[4], swz[4];
#pragma unroll
        for (int mt = 0; mt < 4; ++mt) {
            int oy = pys[mt] + dy, ox = pxs[mt] + dx;
            bool v = prow[mt] && ((unsigned)oy < 7u) && ((unsigned)ox < 7u);
            int np = oy * 7 + ox;
            roff[mt] = v ? np * 512 : TILE;
            swz[mt]  = v ? ((np & 7) << 4) : 16;
        }
#pragma unroll
        for (int c8 = 0; c8 < 8; ++c8) {
            int it  = t * 8 + c8;
            int itn = (it + 2 <= 71) ? it + 2 : 71;
            bf16x8 n0 = *(const bf16x8*)(bp0 + itn * 32);
            bf16x8 n1 = *(const bf16x8*)(bp1 + itn * 32);
            bf16x8 b0 = (c8 & 1) ? b0B : b0A;
            bf16x8 b1 = (c8 & 1) ? b1B : b1A;
            int kb = c8 * 64 + lg16;
#pragma unroll
            for (int mt = 0; mt < 4; ++mt) {
                bf16x8 a = *(const bf16x8*)(lds + roff[mt] + (kb ^ swz[mt]));
                acc[mt][0] = __builtin_amdgcn_mfma_f32_16x16x32_bf16(a, b0, acc[mt][0], 0, 0, 0);
                acc[mt][1] = __builtin_amdgcn_mfma_f32_16x16x32_bf16(a, b1, acc[mt][1], 0, 0, 0);
            }
            if (c8 & 1) { b0B = n0; b1B = n1; }
            else        { b0A = n0; b1A = n1; }
        }
    }

    // ---- epilogue ----
    float pb0 = post_b[co0], pb1 = post_b[co1];
    float* og = out + (size_t)roi * (NPIX * CCH);
#pragma unroll
    for (int mt = 0; mt < 4; ++mt)
#pragma unroll
        for (int r = 0; r < 4; ++r) {
            int pix = mt * 16 + lgrp * 4 + r;
            if (pix < NPIX) {
                og[co0 * NPIX + pix] = fmaxf(acc[mt][0][r] + pb0, 0.f);
                og[co1 * NPIX + pix] = fmaxf(acc[mt][1][r] + pb1, 0.f);
            }
        }
}

// ============================================================================
// Fallback: R7 monolithic kernel (used only if ws too small)
// ============================================================================
__launch_bounds__(512, 4)
__global__ void fused_roi_kernel(const float* __restrict__ rois,
                                 const unsigned short* __restrict__ nh0,
                                 const unsigned short* __restrict__ nh1,
                                 const unsigned short* __restrict__ nh2,
                                 const unsigned short* __restrict__ nh3,
                                 const float* __restrict__ raw0,
                                 const float* __restrict__ raw1,
                                 const float* __restrict__ raw2,
                                 const float* __restrict__ raw3,
                                 int modes,
                                 const unsigned short* __restrict__ btpre,
                                 const unsigned short* __restrict__ btpost,
                                 const float* __restrict__ pre_b,
                                 const float* __restrict__ post_b,
                                 float* __restrict__ out) {
    __shared__ __align__(16) char lds[LDS2];

    int roi  = blockIdx.x;
    int tid  = threadIdx.x;
    int lane = tid & 63;
    int wv   = tid >> 6;
    int lrow = lane & 15;
    int lgrp = lane >> 4;
    int ch0  = lane * 4;
    int co0  = wv * 16 + lrow;
    int co1  = co0 + 128;

    if (tid < 128) ((float*)(lds + ZOFF2))[tid] = 0.f;

    const float* rp = rois + (size_t)roi * 6;
    int   bidx = (int)rp[0];
    float cx0 = rp[1], cy0 = rp[2], rw0 = rp[3], rh0 = rp[4], th = rp[5];
    float ct = cosf(th), st = sinf(th);

    const unsigned short* nh[4] = {nh0, nh1, nh2, nh3};
    const float* raw[4] = {raw0, raw1, raw2, raw3};
    const int Hs[4] = {256, 128, 64, 32};
    const float scl[4] = {0.25f, 0.125f, 0.0625f, 0.03125f};

    auto ra_pair = [&](int p) {
        int ml = wv & 1;
        int gl = p * 2 + ml;
        int H = Hs[gl], W = H;
        float s = scl[gl];
        float cx = cx0 * s, cy = cy0 * s, rw = rw0 * s, rh = rh0 * s;
        float bw = rw * (1.0f / P), bh = rh * (1.0f / P);
        float fH = (float)H, fW = (float)W;
        bool staged = (modes >> gl) & 1;
        const unsigned short* f = nh[gl];
        const float* fr = raw[gl];
        for (int bin = (wv >> 1); bin < NPIX; bin += 4) {
            int py = bin / 7, px = bin - py * 7;
            float a0 = 0.f, a1 = 0.f, a2 = 0.f, a3 = 0.f;
#pragma unroll
            for (int smp = 0; smp < 4; ++smp) {
                int sy = smp >> 1, sx = smp & 1;
                float offy = (float)py + 0.25f + 0.5f * (float)sy;
                float offx = (float)px + 0.25f + 0.5f * (float)sx;
                float yy = offy * bh - rh * 0.5f;
                float xx = offx * bw - rw * 0.5f;
                float X = xx * ct + yy * st + cx;
                float Y = yy * ct - xx * st + cy;
                if (Y > -1.0f && Y < fH && X > -1.0f && X < fW) {
                    float Yc = fmaxf(Y, 0.f), Xc = fmaxf(X, 0.f);
                    int y0 = min((int)Yc, H - 1);
                    int x0 = min((int)Xc, W - 1);
                    int y1 = min(y0 + 1, H - 1), x1 = min(x0 + 1, W - 1);
                    if (y0 >= H - 1) Yc = (float)(H - 1);
                    if (x0 >= W - 1) Xc = (float)(W - 1);
                    float ly = Yc - (float)y0, lx = Xc - (float)x0;
                    float hy = 1.f - ly, hx = 1.f - lx;
                    float w00 = hy * hx, w01 = hy * lx, w10 = ly * hx, w11 = ly * lx;
                    if (staged) {
                        size_t r0 = (size_t)(bidx * H + y0) * W;
                        size_t r1 = (size_t)(bidx * H + y1) * W;
                        uint2 u00 = *(const uint2*)(f + ((r0 + x0) << 8) + ch0);
                        uint2 u01 = *(const uint2*)(f + ((r0 + x1) << 8) + ch0);
                        uint2 u10 = *(const uint2*)(f + ((r1 + x0) << 8) + ch0);
                        uint2 u11 = *(const uint2*)(f + ((r1 + x1) << 8) + ch0);
                        a0 += w00 * blo(u00.x) + w01 * blo(u01.x) + w10 * blo(u10.x) + w11 * blo(u11.x);
                        a1 += w00 * bhi(u00.x) + w01 * bhi(u01.x) + w10 * bhi(u10.x) + w11 * bhi(u11.x);
                        a2 += w00 * blo(u00.y) + w01 * blo(u01.y) + w10 * blo(u10.y) + w11 * blo(u11.y);
                        a3 += w00 * bhi(u00.y) + w01 * bhi(u01.y) + w10 * bhi(u10.y) + w11 * bhi(u11.y);
                    } else {
                        size_t hw = (size_t)H * W;
                        size_t i00 = (size_t)y0 * W + x0, i01 = (size_t)y0 * W + x1;
                        size_t i10 = (size_t)y1 * W + x0, i11 = (size_t)y1 * W + x1;
                        const float* fp0 = fr + ((size_t)bidx * CCH + ch0) * hw;
                        float* accp[4] = {&a0, &a1, &a2, &a3};
#pragma unroll
                        for (int cc = 0; cc < 4; ++cc) {
                            const float* fp = fp0 + (size_t)cc * hw;
                            *accp[cc] += w00 * fp[i00] + w01 * fp[i01] + w10 * fp[i10] + w11 * fp[i11];
                        }
                    }
                }
            }
            unsigned int q01 = (unsigned)f2bf(a0 * 0.25f) | ((unsigned)f2bf(a1 * 0.25f) << 16);
            unsigned int q23 = (unsigned)f2bf(a2 * 0.25f) | ((unsigned)f2bf(a3 * 0.25f) << 16);
            int off = ml * TILE + bin * 512 + ((lane * 8) ^ ((bin & 7) << 4));
            *(uint2*)(lds + off) = make_uint2(q01, q23);
        }
    };

    int pys[4], pxs[4];
    bool prow[4];
#pragma unroll
    for (int mt = 0; mt < 4; ++mt) {
        int pix = mt * 16 + lrow;
        pys[mt] = pix / 7;
        pxs[mt] = pix - pys[mt] * 7;
        prow[mt] = pix < NPIX;
    }
    int lg16 = lgrp * 16;

    auto conv_pair = [&](const unsigned short* __restrict__ Bt, f32x4 (&acc)[2][4][2]) {
        const f32x4 FZ = {0.f, 0.f, 0.f, 0.f};
#pragma unroll
        for (int lv = 0; lv < 2; ++lv)
#pragma unroll
            for (int mt = 0; mt < 4; ++mt) {
                acc[lv][mt][0] = FZ; acc[lv][mt][1] = FZ;
            }
        const unsigned short* bp0 = Bt + (size_t)co0 * KTOT + lgrp * 8;
        const unsigned short* bp1 = Bt + (size_t)co1 * KTOT + lgrp * 8;
        for (int t = 0; t < 9; ++t) {
            int dy = t / 3 - 1, dx = (t % 3) - 1;
            int roff[4], swz[4];
#pragma unroll
            for (int mt = 0; mt < 4; ++mt) {
                int oy = pys[mt] + dy, ox = pxs[mt] + dx;
                bool v = prow[mt] && ((unsigned)oy < 7u) && ((unsigned)ox < 7u);
                int np = oy * 7 + ox;
                roff[mt] = v ? np * 512 : ZOFF2;
                swz[mt]  = v ? ((np & 7) << 4) : 16;
            }
#pragma unroll
            for (int c8 = 0; c8 < 8; ++c8) {
                int kb = c8 * 64 + lg16;
                int ke = (t * 8 + c8) * 32;
                bf16x8 b0 = *(const bf16x8*)(bp0 + ke);
                bf16x8 b1 = *(const bf16x8*)(bp1 + ke);
#pragma unroll
                for (int mt = 0; mt < 4; ++mt) {
                    int lo = kb ^ swz[mt];
                    bf16x8 a0 = *(const bf16x8*)(lds + roff[mt] + lo);
                    bf16x8 a1 = *(const bf16x8*)(lds + (roff[mt] == ZOFF2 ? ZOFF2 : roff[mt] + TILE) + lo);
                    acc[0][mt][0] = __builtin_amdgcn_mfma_f32_16x16x32_bf16(a0, b0, acc[0][mt][0], 0, 0, 0);
                    acc[0][mt][1] = __builtin_amdgcn_mfma_f32_16x16x32_bf16(a0, b1, acc[0][mt][1], 0, 0, 0);
                    acc[1][mt][0] = __builtin_amdgcn_mfma_f32_16x16x32_bf16(a1, b0, acc[1][mt][0], 0, 0, 0);
                    acc[1][mt][1] = __builtin_amdgcn_mfma_f32_16x16x32_bf16(a1, b1, acc[1][mt][1], 0, 0, 0);
                }
            }
        }
    };

    float bs0 = pre_b[co0], bs1 = pre_b[co1];
    f32x4 sum[4][2];
    {
        const f32x4 FZ = {0.f, 0.f, 0.f, 0.f};
#pragma unroll
        for (int mt = 0; mt < 4; ++mt) { sum[mt][0] = FZ; sum[mt][1] = FZ; }
    }

    ra_pair(0);
    __syncthreads();
    {
        f32x4 acc[2][4][2];
        conv_pair(btpre, acc);
#pragma unroll
        for (int lv = 0; lv < 2; ++lv)
#pragma unroll
            for (int mt = 0; mt < 4; ++mt)
#pragma unroll
                for (int r = 0; r < 4; ++r) {
                    sum[mt][0][r] += fmaxf(acc[lv][mt][0][r] + bs0, 0.f);
                    sum[mt][1][r] += fmaxf(acc[lv][mt][1][r] + bs1, 0.f);
                }
    }
    __syncthreads();

    ra_pair(1);
    __syncthreads();
    {
        f32x4 acc[2][4][2];
        conv_pair(btpre, acc);
#pragma unroll
        for (int lv = 0; lv < 2; ++lv)
#pragma unroll
            for (int mt = 0; mt < 4; ++mt)
#pragma unroll
                for (int r = 0; r < 4; ++r) {
                    sum[mt][0][r] += fmaxf(acc[lv][mt][0][r] + bs0, 0.f);
                    sum[mt][1][r] += fmaxf(acc[lv][mt][1][r] + bs1, 0.f);
                }
    }
    __syncthreads();

#pragma unroll
    for (int nt = 0; nt < 2; ++nt) {
        int co = nt ? co1 : co0;
#pragma unroll
        for (int mt = 0; mt < 4; ++mt)
#pragma unroll
            for (int r = 0; r < 4; ++r) {
                int pix = mt * 16 + lgrp * 4 + r;
                if (pix < NPIX) {
                    int off = pix * 512 + ((co * 2) ^ ((pix & 7) << 4));
                    *(unsigned short*)(lds + off) = f2bf(sum[mt][nt][r]);
                }
            }
    }
    __syncthreads();

    f32x4 pacc[4][2];
    {
        const f32x4 FZ = {0.f, 0.f, 0.f, 0.f};
#pragma unroll
        for (int mt = 0; mt < 4; ++mt) { pacc[mt][0] = FZ; pacc[mt][1] = FZ; }
    }
    {
        const unsigned short* bp0 = btpost + (size_t)co0 * KTOT + lgrp * 8;
        const unsigned short* bp1 = btpost + (size_t)co1 * KTOT + lgrp * 8;
        for (int t = 0; t < 9; ++t) {
            int dy = t / 3 - 1, dx = (t % 3) - 1;
            int roff[4], swz[4];
#pragma unroll
            for (int mt = 0; mt < 4; ++mt) {
                int oy = pys[mt] + dy, ox = pxs[mt] + dx;
                bool v = prow[mt] && ((unsigned)oy < 7u) && ((unsigned)ox < 7u);
                int np = oy * 7 + ox;
                roff[mt] = v ? np * 512 : ZOFF2;
                swz[mt]  = v ? ((np & 7) << 4) : 16;
            }
#pragma unroll
            for (int c8 = 0; c8 < 8; ++c8) {
                int kb = c8 * 64 + lg16;
                int ke = (t * 8 + c8) * 32;
                bf16x8 b0 = *(const bf16x8*)(bp0 + ke);
                bf16x8 b1 = *(const bf16x8*)(bp1 + ke);
#pragma unroll
                for (int mt = 0; mt < 4; ++mt) {
                    bf16x8 a = *(const bf16x8*)(lds + roff[mt] + (kb ^ swz[mt]));
                    pacc[mt][0] = __builtin_amdgcn_mfma_f32_16x16x32_bf16(a, b0, pacc[mt][0], 0, 0, 0);
                    pacc[mt][1] = __builtin_amdgcn_mfma_f32_16x16x32_bf16(a, b1, pacc[mt][1], 0, 0, 0);
                }
            }
        }
    }

    float pb0 = post_b[co0], pb1 = post_b[co1];
    float* og = out + (size_t)roi * (NPIX * CCH);
#pragma unroll
    for (int mt = 0; mt < 4; ++mt)
#pragma unroll
        for (int r = 0; r < 4; ++r) {
            int pix = mt * 16 + lgrp * 4 + r;
            if (pix < NPIX) {
                og[co0 * NPIX + pix] = fmaxf(pacc[mt][0][r] + pb0, 0.f);
                og[co1 * NPIX + pix] = fmaxf(pacc[mt][1][r] + pb1, 0.f);
            }
        }
}

extern "C" void kernel_launch(void* const* d_in, const int* in_sizes, int n_in,
                              void* d_out, int out_size, void* d_ws, size_t ws_size,
                              hipStream_t stream) {
    const float* feats[4] = {(const float*)d_in[0], (const float*)d_in[1],
                             (const float*)d_in[2], (const float*)d_in[3]};
    const float* rois   = (const float*)d_in[4];
    const float* pre_w  = (const float*)d_in[5];
    const float* pre_b  = (const float*)d_in[6];
    const float* post_w = (const float*)d_in[7];
    const float* post_b = (const float*)d_in[8];

    int nroi = in_sizes[4] / 6;
    int B = in_sizes[0] / (CCH * 256 * 256);
    const int Hs[4] = {256, 128, 64, 32};

    char* ws = (char*)d_ws;
    size_t off = 0;
    auto take = [&](size_t bytes) -> void* {
        void* p = ws + off;
        off += (bytes + 255) & ~(size_t)255;
        return p;
    };
    unsigned short* btpre  = (unsigned short*)take((size_t)CCH * KTOT * 2);
    unsigned short* btpost = (unsigned short*)take((size_t)CCH * KTOT * 2);

    size_t abytes = (size_t)4 * nroi * TILE;
    size_t pbytes = (size_t)nroi * NPIX * CCH * 4;   // one f32 partial slot
    size_t aal = (abytes + 255) & ~(size_t)255;
    size_t pal = (pbytes + 255) & ~(size_t)255;
    bool fastpath = (off + aal + 2 * pal) <= ws_size;

    unsigned short* atile = nullptr;
    float* part0 = nullptr;
    float* part1 = nullptr;
    unsigned short* nh[4] = {nullptr, nullptr, nullptr, nullptr};
    int modes = 0;

    if (fastpath) {
        atile = (unsigned short*)take(abytes);
        size_t region = off;
        part0 = (float*)(ws + region);
        part1 = (float*)(ws + region + pal);
        // features aliased into the same region (dead after ra_stage)
        for (int l = 0; l < 4; ++l) {
            size_t need = (size_t)B * Hs[l] * Hs[l] * CCH * 2;
            if (off + need <= ws_size) {
                nh[l] = (unsigned short*)take(need);
                modes |= (1 << l);
            }
        }
    } else {
        for (int l = 0; l < 4; ++l) {
            size_t need = (size_t)B * Hs[l] * Hs[l] * CCH * 2;
            if (off + need <= ws_size) {
                nh[l] = (unsigned short*)take(need);
                modes |= (1 << l);
            }
        }
    }

    for (int l = 0; l < 4; ++l) {
        if (!(modes & (1 << l))) continue;
        dim3 g(Hs[l] / 32, CCH / 32, B * Hs[l]);
        nhwc_transpose_kernel<<<g, 256, 0, stream>>>(feats[l], nh[l], Hs[l], Hs[l]);
    }
    wtrans_kernel<<<(2 * CCH * KTOT + 255) / 256, 256, 0, stream>>>(pre_w, post_w, btpre, btpost);

    if (fastpath) {
        ra_stage_kernel<<<4 * nroi, 256, 0, stream>>>(rois, nh[0], nh[1], nh[2], nh[3],
                                                      feats[0], feats[1], feats[2], feats[3],
                                                      modes, atile, nroi);
        pre_conv_pair_kernel<<<2 * nroi, 512, 0, stream>>>(atile, btpre, pre_b,
                                                           part0, part1, nroi);
        post_conv_kernel<<<2 * nroi, 256, 0, stream>>>(part0, part1, btpost, post_b,
                                                       (float*)d_out);
    } else {
        fused_roi_kernel<<<nroi, 512, 0, stream>>>(rois, nh[0], nh[1], nh[2], nh[3],
                                                   feats[0], feats[1], feats[2], feats[3],
                                                   modes, btpre, btpost, pre_b, post_b,
                                                   (float*)d_out);
    }
}

// Round 14
// 395.153 us; speedup vs baseline: 1.0557x; 1.0557x over previous
//
#include <hip/hip_runtime.h>
#include <hip/hip_bf16.h>

#define P 7
#define CCH 256
#define NPIX 49
#define KTOT 2304
#define TILE 25088              // 49 * 512 bytes per level tile
#define ZOFF2 (2 * TILE)        // zero row offset
#define LDS2 (2 * TILE + 512)   // two tiles + zero row

typedef __bf16 bf16x8 __attribute__((ext_vector_type(8)));
typedef float f32x4 __attribute__((ext_vector_type(4)));

__device__ __forceinline__ unsigned short f2bf(float f) {
    unsigned int u = __float_as_uint(f);
    unsigned int r = (u + 0x7fffu + ((u >> 16) & 1u)) >> 16;
    return (unsigned short)r;
}
__device__ __forceinline__ float blo(unsigned int u) { return __uint_as_float(u << 16); }
__device__ __forceinline__ float bhi(unsigned int u) { return __uint_as_float(u & 0xffff0000u); }

// NCHW f32 -> NHWC bf16 (per level), 32x32 tile transpose over (c,x)
__global__ void nhwc_transpose_kernel(const float* __restrict__ src,
                                      unsigned short* __restrict__ dst,
                                      int H, int W) {
    __shared__ float tile[32][33];
    int x0 = blockIdx.x * 32;
    int c0 = blockIdx.y * 32;
    int bz = blockIdx.z;            // b*H + y
    int b = bz / H, y = bz - b * H;
    int tx = threadIdx.x & 31, ty = threadIdx.x >> 5;   // 256 threads
    const float* s = src + ((size_t)(b * CCH + c0) * H + y) * W + x0;
#pragma unroll
    for (int j = 0; j < 4; ++j) {
        int row = ty + j * 8;
        tile[row][tx] = s[(size_t)row * H * W + tx];
    }
    __syncthreads();
    unsigned short* d = dst + ((size_t)bz * W + x0) * CCH + c0;
#pragma unroll
    for (int j = 0; j < 4; ++j) {
        int row = ty + j * 8;
        d[(size_t)row * CCH + tx] = f2bf(tile[tx][row]);
    }
}

// w[co][ci][ky][kx] f32 -> Bt[co][k] bf16 with k = (ky*3+kx)*256 + ci
__global__ void wtrans_kernel(const float* __restrict__ pre_w,
                              const float* __restrict__ post_w,
                              unsigned short* __restrict__ btpre,
                              unsigned short* __restrict__ btpost) {
    int idx = blockIdx.x * 256 + threadIdx.x;
    const int total = CCH * KTOT;
    if (idx >= 2 * total) return;
    const float* w = pre_w;
    unsigned short* o = btpre;
    int r = idx;
    if (r >= total) { r -= total; w = post_w; o = btpost; }
    int co = r / KTOT, k = r - co * KTOT;
    int t = k >> 8, ci = k & 255;
    o[r] = f2bf(w[(size_t)(co * CCH + ci) * 9 + t]);
}

// ============================================================================
// Monolithic fused kernel (R7 structure + R12's proven B ping-pong prefetch).
// One block = one roi. 512 thr = 8 waves, nt=2 (co, co+128).
// Phases: RA{0,1} -> convA (2 B-loads : 16 MFMA, B prefetch d1)
//         -> RA{2,3} -> convB -> stage f32 sum (single bf16 rounding)
//         -> post-conv (B prefetch d1).
// ============================================================================
__launch_bounds__(512, 4)
__global__ void fused_roi_kernel(const float* __restrict__ rois,
                                 const unsigned short* __restrict__ nh0,
                                 const unsigned short* __restrict__ nh1,
                                 const unsigned short* __restrict__ nh2,
                                 const unsigned short* __restrict__ nh3,
                                 const float* __restrict__ raw0,
                                 const float* __restrict__ raw1,
                                 const float* __restrict__ raw2,
                                 const float* __restrict__ raw3,
                                 int modes,
                                 const unsigned short* __restrict__ btpre,
                                 const unsigned short* __restrict__ btpost,
                                 const float* __restrict__ pre_b,
                                 const float* __restrict__ post_b,
                                 float* __restrict__ out) {
    __shared__ __align__(16) char lds[LDS2];

    int roi  = blockIdx.x;
    int tid  = threadIdx.x;
    int lane = tid & 63;
    int wv   = tid >> 6;
    int lrow = lane & 15;
    int lgrp = lane >> 4;
    int ch0  = lane * 4;
    int co0  = wv * 16 + lrow;
    int co1  = co0 + 128;

    if (tid < 128) ((float*)(lds + ZOFF2))[tid] = 0.f;

    const float* rp = rois + (size_t)roi * 6;
    int   bidx = (int)rp[0];
    float cx0 = rp[1], cy0 = rp[2], rw0 = rp[3], rh0 = rp[4], th = rp[5];
    float ct = cosf(th), st = sinf(th);

    const unsigned short* nh[4] = {nh0, nh1, nh2, nh3};
    const float* raw[4] = {raw0, raw1, raw2, raw3};
    const int Hs[4] = {256, 128, 64, 32};
    const float scl[4] = {0.25f, 0.125f, 0.0625f, 0.03125f};

    auto ra_pair = [&](int p) {
        int ml = wv & 1;
        int gl = p * 2 + ml;
        int H = Hs[gl], W = H;
        float s = scl[gl];
        float cx = cx0 * s, cy = cy0 * s, rw = rw0 * s, rh = rh0 * s;
        float bw = rw * (1.0f / P), bh = rh * (1.0f / P);
        float fH = (float)H, fW = (float)W;
        bool staged = (modes >> gl) & 1;
        const unsigned short* f = nh[gl];
        const float* fr = raw[gl];
        for (int bin = (wv >> 1); bin < NPIX; bin += 4) {
            int py = bin / 7, px = bin - py * 7;
            float a0 = 0.f, a1 = 0.f, a2 = 0.f, a3 = 0.f;
#pragma unroll
            for (int smp = 0; smp < 4; ++smp) {
                int sy = smp >> 1, sx = smp & 1;
                float offy = (float)py + 0.25f + 0.5f * (float)sy;
                float offx = (float)px + 0.25f + 0.5f * (float)sx;
                float yy = offy * bh - rh * 0.5f;
                float xx = offx * bw - rw * 0.5f;
                float X = xx * ct + yy * st + cx;
                float Y = yy * ct - xx * st + cy;
                if (Y > -1.0f && Y < fH && X > -1.0f && X < fW) {
                    float Yc = fmaxf(Y, 0.f), Xc = fmaxf(X, 0.f);
                    int y0 = min((int)Yc, H - 1);
                    int x0 = min((int)Xc, W - 1);
                    int y1 = min(y0 + 1, H - 1), x1 = min(x0 + 1, W - 1);
                    if (y0 >= H - 1) Yc = (float)(H - 1);
                    if (x0 >= W - 1) Xc = (float)(W - 1);
                    float ly = Yc - (float)y0, lx = Xc - (float)x0;
                    float hy = 1.f - ly, hx = 1.f - lx;
                    float w00 = hy * hx, w01 = hy * lx, w10 = ly * hx, w11 = ly * lx;
                    if (staged) {
                        size_t r0 = (size_t)(bidx * H + y0) * W;
                        size_t r1 = (size_t)(bidx * H + y1) * W;
                        uint2 u00 = *(const uint2*)(f + ((r0 + x0) << 8) + ch0);
                        uint2 u01 = *(const uint2*)(f + ((r0 + x1) << 8) + ch0);
                        uint2 u10 = *(const uint2*)(f + ((r1 + x0) << 8) + ch0);
                        uint2 u11 = *(const uint2*)(f + ((r1 + x1) << 8) + ch0);
                        a0 += w00 * blo(u00.x) + w01 * blo(u01.x) + w10 * blo(u10.x) + w11 * blo(u11.x);
                        a1 += w00 * bhi(u00.x) + w01 * bhi(u01.x) + w10 * bhi(u10.x) + w11 * bhi(u11.x);
                        a2 += w00 * blo(u00.y) + w01 * blo(u01.y) + w10 * blo(u10.y) + w11 * blo(u11.y);
                        a3 += w00 * bhi(u00.y) + w01 * bhi(u01.y) + w10 * bhi(u10.y) + w11 * bhi(u11.y);
                    } else {
                        size_t hw = (size_t)H * W;
                        size_t i00 = (size_t)y0 * W + x0, i01 = (size_t)y0 * W + x1;
                        size_t i10 = (size_t)y1 * W + x0, i11 = (size_t)y1 * W + x1;
                        const float* fp0 = fr + ((size_t)bidx * CCH + ch0) * hw;
                        float* accp[4] = {&a0, &a1, &a2, &a3};
#pragma unroll
                        for (int cc = 0; cc < 4; ++cc) {
                            const float* fp = fp0 + (size_t)cc * hw;
                            *accp[cc] += w00 * fp[i00] + w01 * fp[i01] + w10 * fp[i10] + w11 * fp[i11];
                        }
                    }
                }
            }
            unsigned int q01 = (unsigned)f2bf(a0 * 0.25f) | ((unsigned)f2bf(a1 * 0.25f) << 16);
            unsigned int q23 = (unsigned)f2bf(a2 * 0.25f) | ((unsigned)f2bf(a3 * 0.25f) << 16);
            int off = ml * TILE + bin * 512 + ((lane * 8) ^ ((bin & 7) << 4));
            *(uint2*)(lds + off) = make_uint2(q01, q23);
        }
    };

    int pys[4], pxs[4];
    bool prow[4];
#pragma unroll
    for (int mt = 0; mt < 4; ++mt) {
        int pix = mt * 16 + lrow;
        pys[mt] = pix / 7;
        pxs[mt] = pix - pys[mt] * 7;
        prow[mt] = pix < NPIX;
    }
    int lg16 = lgrp * 16;

    // conv over the two resident tiles: 2 B-loads feed 16 MFMAs, B prefetch d1
    auto conv_pair = [&](const unsigned short* __restrict__ Bt, f32x4 (&acc)[2][4][2]) {
        const f32x4 FZ = {0.f, 0.f, 0.f, 0.f};
#pragma unroll
        for (int lv = 0; lv < 2; ++lv)
#pragma unroll
            for (int mt = 0; mt < 4; ++mt) {
                acc[lv][mt][0] = FZ; acc[lv][mt][1] = FZ;
            }
        const unsigned short* bp0 = Bt + (size_t)co0 * KTOT + lgrp * 8;
        const unsigned short* bp1 = Bt + (size_t)co1 * KTOT + lgrp * 8;
        bf16x8 b0 = *(const bf16x8*)(bp0);
        bf16x8 b1 = *(const bf16x8*)(bp1);
        for (int t = 0; t < 9; ++t) {
            int dy = t / 3 - 1, dx = (t % 3) - 1;
            int roff[4], swz[4];
#pragma unroll
            for (int mt = 0; mt < 4; ++mt) {
                int oy = pys[mt] + dy, ox = pxs[mt] + dx;
                bool v = prow[mt] && ((unsigned)oy < 7u) && ((unsigned)ox < 7u);
                int np = oy * 7 + ox;
                roff[mt] = v ? np * 512 : ZOFF2;
                swz[mt]  = v ? ((np & 7) << 4) : 16;
            }
#pragma unroll
            for (int c8 = 0; c8 < 8; ++c8) {
                int it  = t * 8 + c8;
                int itn = (it < 71) ? it + 1 : 71;
                bf16x8 n0 = *(const bf16x8*)(bp0 + itn * 32);
                bf16x8 n1 = *(const bf16x8*)(bp1 + itn * 32);
                int kb = c8 * 64 + lg16;
#pragma unroll
                for (int mt = 0; mt < 4; ++mt) {
                    int lo = kb ^ swz[mt];
                    bf16x8 a0 = *(const bf16x8*)(lds + roff[mt] + lo);
                    bf16x8 a1 = *(const bf16x8*)(lds +
                                  (roff[mt] == ZOFF2 ? ZOFF2 : roff[mt] + TILE) + lo);
                    acc[0][mt][0] = __builtin_amdgcn_mfma_f32_16x16x32_bf16(a0, b0, acc[0][mt][0], 0, 0, 0);
                    acc[0][mt][1] = __builtin_amdgcn_mfma_f32_16x16x32_bf16(a0, b1, acc[0][mt][1], 0, 0, 0);
                    acc[1][mt][0] = __builtin_amdgcn_mfma_f32_16x16x32_bf16(a1, b0, acc[1][mt][0], 0, 0, 0);
                    acc[1][mt][1] = __builtin_amdgcn_mfma_f32_16x16x32_bf16(a1, b1, acc[1][mt][1], 0, 0, 0);
                }
                b0 = n0; b1 = n1;
            }
        }
    };

    float bs0 = pre_b[co0], bs1 = pre_b[co1];
    f32x4 sum[4][2];
    {
        const f32x4 FZ = {0.f, 0.f, 0.f, 0.f};
#pragma unroll
        for (int mt = 0; mt < 4; ++mt) { sum[mt][0] = FZ; sum[mt][1] = FZ; }
    }

    // ===== pair 0: levels 0,1 =====
    ra_pair(0);
    __syncthreads();
    {
        f32x4 acc[2][4][2];
        conv_pair(btpre, acc);
#pragma unroll
        for (int lv = 0; lv < 2; ++lv)
#pragma unroll
            for (int mt = 0; mt < 4; ++mt)
#pragma unroll
                for (int r = 0; r < 4; ++r) {
                    sum[mt][0][r] += fmaxf(acc[lv][mt][0][r] + bs0, 0.f);
                    sum[mt][1][r] += fmaxf(acc[lv][mt][1][r] + bs1, 0.f);
                }
    }
    __syncthreads();   // conv A reads done before RA overwrites tiles

    // ===== pair 1: levels 2,3 =====
    ra_pair(1);
    __syncthreads();
    {
        f32x4 acc[2][4][2];
        conv_pair(btpre, acc);
#pragma unroll
        for (int lv = 0; lv < 2; ++lv)
#pragma unroll
            for (int mt = 0; mt < 4; ++mt)
#pragma unroll
                for (int r = 0; r < 4; ++r) {
                    sum[mt][0][r] += fmaxf(acc[lv][mt][0][r] + bs0, 0.f);
                    sum[mt][1][r] += fmaxf(acc[lv][mt][1][r] + bs1, 0.f);
                }
    }
    __syncthreads();   // conv B reads done before staging overwrites tile 0

    // ---- stage f32 sum -> bf16 tile 0 (single rounding) ----
#pragma unroll
    for (int nt = 0; nt < 2; ++nt) {
        int co = nt ? co1 : co0;
#pragma unroll
        for (int mt = 0; mt < 4; ++mt)
#pragma unroll
            for (int r = 0; r < 4; ++r) {
                int pix = mt * 16 + lgrp * 4 + r;
                if (pix < NPIX) {
                    int off = pix * 512 + ((co * 2) ^ ((pix & 7) << 4));
                    *(unsigned short*)(lds + off) = f2bf(sum[mt][nt][r]);
                }
            }
    }
    __syncthreads();

    // ---- post conv on tile 0 (nt=2, B prefetch d1) ----
    f32x4 pacc[4][2];
    {
        const f32x4 FZ = {0.f, 0.f, 0.f, 0.f};
#pragma unroll
        for (int mt = 0; mt < 4; ++mt) { pacc[mt][0] = FZ; pacc[mt][1] = FZ; }
    }
    {
        const unsigned short* bp0 = btpost + (size_t)co0 * KTOT + lgrp * 8;
        const unsigned short* bp1 = btpost + (size_t)co1 * KTOT + lgrp * 8;
        bf16x8 b0 = *(const bf16x8*)(bp0);
        bf16x8 b1 = *(const bf16x8*)(bp1);
        for (int t = 0; t < 9; ++t) {
            int dy = t / 3 - 1, dx = (t % 3) - 1;
            int roff[4], swz[4];
#pragma unroll
            for (int mt = 0; mt < 4; ++mt) {
                int oy = pys[mt] + dy, ox = pxs[mt] + dx;
                bool v = prow[mt] && ((unsigned)oy < 7u) && ((unsigned)ox < 7u);
                int np = oy * 7 + ox;
                roff[mt] = v ? np * 512 : ZOFF2;
                swz[mt]  = v ? ((np & 7) << 4) : 16;
            }
#pragma unroll
            for (int c8 = 0; c8 < 8; ++c8) {
                int it  = t * 8 + c8;
                int itn = (it < 71) ? it + 1 : 71;
                bf16x8 n0 = *(const bf16x8*)(bp0 + itn * 32);
                bf16x8 n1 = *(const bf16x8*)(bp1 + itn * 32);
                int kb = c8 * 64 + lg16;
#pragma unroll
                for (int mt = 0; mt < 4; ++mt) {
                    bf16x8 a = *(const bf16x8*)(lds + roff[mt] + (kb ^ swz[mt]));
                    pacc[mt][0] = __builtin_amdgcn_mfma_f32_16x16x32_bf16(a, b0, pacc[mt][0], 0, 0, 0);
                    pacc[mt][1] = __builtin_amdgcn_mfma_f32_16x16x32_bf16(a, b1, pacc[mt][1], 0, 0, 0);
                }
                b0 = n0; b1 = n1;
            }
        }
    }

    // ---- epilogue: bias + relu -> f32 out ----
    float pb0 = post_b[co0], pb1 = post_b[co1];
    float* og = out + (size_t)roi * (NPIX * CCH);
#pragma unroll
    for (int mt = 0; mt < 4; ++mt)
#pragma unroll
        for (int r = 0; r < 4; ++r) {
            int pix = mt * 16 + lgrp * 4 + r;
            if (pix < NPIX) {
                og[co0 * NPIX + pix] = fmaxf(pacc[mt][0][r] + pb0, 0.f);
                og[co1 * NPIX + pix] = fmaxf(pacc[mt][1][r] + pb1, 0.f);
            }
        }
}

extern "C" void kernel_launch(void* const* d_in, const int* in_sizes, int n_in,
                              void* d_out, int out_size, void* d_ws, size_t ws_size,
                              hipStream_t stream) {
    const float* feats[4] = {(const float*)d_in[0], (const float*)d_in[1],
                             (const float*)d_in[2], (const float*)d_in[3]};
    const float* rois   = (const float*)d_in[4];
    const float* pre_w  = (const float*)d_in[5];
    const float* pre_b  = (const float*)d_in[6];
    const float* post_w = (const float*)d_in[7];
    const float* post_b = (const float*)d_in[8];

    int nroi = in_sizes[4] / 6;
    int B = in_sizes[0] / (CCH * 256 * 256);
    const int Hs[4] = {256, 128, 64, 32};

    // ws plan: weights, then feature levels greedily
    char* ws = (char*)d_ws;
    size_t off = 0;
    auto take = [&](size_t bytes) -> void* {
        void* p = ws + off;
        off += (bytes + 255) & ~(size_t)255;
        return p;
    };
    unsigned short* btpre  = (unsigned short*)take((size_t)CCH * KTOT * 2);
    unsigned short* btpost = (unsigned short*)take((size_t)CCH * KTOT * 2);

    unsigned short* nh[4] = {nullptr, nullptr, nullptr, nullptr};
    int modes = 0;
    for (int l = 0; l < 4; ++l) {
        size_t need = (size_t)B * Hs[l] * Hs[l] * CCH * 2;
        if (off + need <= ws_size) {
            nh[l] = (unsigned short*)take(need);
            modes |= (1 << l);
        }
    }

    for (int l = 0; l < 4; ++l) {
        if (!(modes & (1 << l))) continue;
        dim3 g(Hs[l] / 32, CCH / 32, B * Hs[l]);
        nhwc_transpose_kernel<<<g, 256, 0, stream>>>(feats[l], nh[l], Hs[l], Hs[l]);
    }
    wtrans_kernel<<<(2 * CCH * KTOT + 255) / 256, 256, 0, stream>>>(pre_w, post_w, btpre, btpost);

    fused_roi_kernel<<<nroi, 512, 0, stream>>>(rois, nh[0], nh[1], nh[2], nh[3],
                                               feats[0], feats[1], feats[2], feats[3],
                                               modes, btpre, btpost, pre_b, post_b,
                                               (float*)d_out);
}